// Round 10
// baseline (366.224 us; speedup 1.0000x reference)
//
#include <hip/hip_runtime.h>
#include <hip/hip_fp16.h>
#include <math.h>

#define N_NODES 50000
#define N_EDGES 600000
#define TOT (N_EDGES + N_NODES)   // 650000 edges incl. self-loops
#define HD 128
#define OUTW 384
#define NEG_SLOPE 0.2f

#define BM 128
#define GB 391          // ceil(50000/128) gemm tiles
#define NCHUNK 49       // ceil(50000/1024)
#define FILLB 256       // fill blocks inside fillgemm dispatch
#define XC 1563         // xcopy blocks appended to agg0 dispatch

// agg slicing: 4 column-slices of 32 cols; 32 nodes/block, 8 lanes/node
#define NSL 4
#define NG 1563         // ceil(50000/32) node-groups
#define AGB2 (NG * NSL) // 6252 agg blocks

// edge_kernel block ranges
#define DBLK 2540       // edge decode + degree count
#define WBLK 64         // W pack
#define SBLK 64         // edge_attr sum
// +1 block: We.ae dots

// ---------- helpers ----------

typedef _Float16 h2_t __attribute__((ext_vector_type(2)));
typedef float f4_t __attribute__((ext_vector_type(4)));   // native vec for nontemporal builtins

static __device__ __forceinline__ float fdot2f(h2_t a, h2_t b, float c){
#if __has_builtin(__builtin_amdgcn_fdot2)
  return __builtin_amdgcn_fdot2(a, b, c, false);
#else
  return fmaf((float)a[0], (float)b[0], fmaf((float)a[1], (float)b[1], c));
#endif
}

static __device__ __forceinline__ void nt_store4(float* p, float a, float b, float c, float d){
  f4_t v = {a, b, c, d};
  __builtin_nontemporal_store(v, (f4_t*)p);
}

static __device__ __forceinline__ int load_edge(const void* ei, int is64, long long off){
  return is64 ? (int)((const long long*)ei)[off] : ((const int*)ei)[off];
}

// ---------- edge/setup kernel (critical-path-only work) ----------
__global__ __launch_bounds__(256) void edge_kernel(const void* ei, int* deg,
                                                   int* __restrict__ src32, int* __restrict__ dst32,
                                                   const float* __restrict__ W0, const float* __restrict__ W1,
                                                   __half2* __restrict__ Wt0, __half2* __restrict__ Wt1,
                                                   const float* __restrict__ eattr, float* scal,
                                                   const float* __restrict__ We0, const float* __restrict__ ae0,
                                                   const float* __restrict__ We1, const float* __restrict__ ae1){
  int b = blockIdx.x;
  int t = threadIdx.x;
  if (b < DBLK){
    __shared__ int s_is64;
    if (t < 64){
      long long v = ((const long long*)ei)[t];
      unsigned long long bad = __ballot(v < 0 || v >= N_NODES);
      if (t == 0) s_is64 = (bad == 0ull) ? 1 : 0;
    }
    __syncthreads();
    int is64 = s_is64;
    int e = b * 256 + t;
    if (e < TOT){
      int d;
      if (e < N_EDGES){
        int s = load_edge(ei, is64, e);
        d = load_edge(ei, is64, (long long)N_EDGES + e);
        src32[e] = s;
        dst32[e] = d;
      } else {
        d = e - N_EDGES;
      }
      atomicAdd(&deg[d], 1);
    }
  } else if (b < DBLK + WBLK){
    int e = (b - DBLK) * 256 + t;             // 0..16383 exact
    const float* W = (e < 8192) ? W0 : W1;
    __half2* Wt = (e < 8192) ? Wt0 : Wt1;
    int i = e & 8191;
    int n = i & 127, k2 = i >> 7;
    float a = W[n * HD + 2 * k2];
    float c = W[n * HD + 2 * k2 + 1];
    Wt[k2 * 128 + n] = __floats2half2_rn(a, c);
  } else if (b < DBLK + WBLK + SBLK){
    int gtid = (b - DBLK - WBLK) * 256 + t;
    float s = 0.f;
    for (int i = gtid; i < N_EDGES; i += SBLK * 256) s += eattr[i];
    #pragma unroll
    for (int o = 32; o > 0; o >>= 1) s += __shfl_down(s, o, 64);
    if ((t & 63) == 0) atomicAdd(&scal[0], s);
  } else {
    int w = t >> 6, lane = t & 63;
    if (w == 1){
      float s = We0[lane] * ae0[lane] + We0[lane + 64] * ae0[lane + 64];
      #pragma unroll
      for (int o = 32; o > 0; o >>= 1) s += __shfl_down(s, o, 64);
      if (lane == 0) scal[1] = s;
    } else if (w == 2){
      float s = We1[lane] * ae1[lane] + We1[lane + 64] * ae1[lane + 64];
      #pragma unroll
      for (int o = 32; o > 0; o >>= 1) s += __shfl_down(s, o, 64);
      if (lane == 0) scal[2] = s;
    }
  }
}

// ---------- fused CSR scan: per-chunk scan + decoupled lookback ----------
__global__ __launch_bounds__(256) void scanfuse_kernel(const int* __restrict__ deg,
                                                       int* __restrict__ rowstart,
                                                       int* __restrict__ rowcur,
                                                       int* chunkflag){
  __shared__ int sums[256];
  __shared__ int soff;
  int bid = blockIdx.x, t = threadIdx.x;
  int base = bid * 1024 + t * 4;
  int v[4];
  #pragma unroll
  for (int i = 0; i < 4; i++) v[i] = (base + i < N_NODES) ? deg[base + i] : 0;
  int tsum = v[0] + v[1] + v[2] + v[3];
  sums[t] = tsum;
  __syncthreads();
  for (int off = 1; off < 256; off <<= 1){
    int add = (t >= off) ? sums[t - off] : 0;
    __syncthreads();
    sums[t] += add;
    __syncthreads();
  }
  int run = sums[t] - tsum;

  if (t == 255)
    __hip_atomic_store(&chunkflag[bid], sums[255] + 1, __ATOMIC_RELEASE, __HIP_MEMORY_SCOPE_AGENT);

  if (t < 64){
    int acc_ = 0;
    for (int j = t; j < bid; j += 64){
      int val;
      long long spins = 0;
      while ((val = __hip_atomic_load(&chunkflag[j], __ATOMIC_ACQUIRE, __HIP_MEMORY_SCOPE_AGENT)) == 0){
        __builtin_amdgcn_s_sleep(1);
        if (++spins > (1LL << 24)) break;
      }
      acc_ += val - 1;
    }
    #pragma unroll
    for (int o = 32; o > 0; o >>= 1) acc_ += __shfl_down(acc_, o, 64);
    if (t == 0) soff = acc_;
  }
  __syncthreads();
  int off = soff;
  #pragma unroll
  for (int i = 0; i < 4; i++){
    if (base + i < N_NODES){
      int r = run + off;
      rowstart[base + i] = r;
      rowcur[base + i] = r;
    }
    run += v[i];
  }
}

// ---------- 512-thread GEMM tile (16 waves/CU at 64KB LDS) ----------
template<bool F32>
__device__ __forceinline__ void gemm_tile512(int tb, int t, __half2* As2, __half2* Wh2,
                                             const void* __restrict__ hin,
                                             const __half2* __restrict__ Wt,
                                             __half* __restrict__ hp_h,
                                             const float* __restrict__ as_,
                                             const float* __restrict__ ad_,
                                             float* __restrict__ ssrc,
                                             float* __restrict__ sdst){
  int tx = t & 15;
  int ty = t >> 4;                 // 0..31
  int rb = tb * BM;

  {
    const float4* src = (const float4*)Wt;
    float4* dst = (float4*)Wh2;
    #pragma unroll
    for (int p = 0; p < 4; p++) dst[t + p * 512] = src[t + p * 512];
  }
  if (F32){
    const float* xin = (const float*)hin;
    #pragma unroll
    for (int p = 0; p < 8; p++){
      int idx = t + p * 512;
      int row = idx >> 5, c4 = idx & 31;
      int gr = rb + row; if (gr >= N_NODES) gr = N_NODES - 1;
      float4 v = *(const float4*)&xin[(size_t)gr * HD + c4 * 4];
      As2[(2 * c4 + 0) * 128 + row] = __floats2half2_rn(v.x, v.y);
      As2[(2 * c4 + 1) * 128 + row] = __floats2half2_rn(v.z, v.w);
    }
  } else {
    const __half* hin16 = (const __half*)hin;
    #pragma unroll
    for (int p = 0; p < 4; p++){
      int idx = t + p * 512;
      int row = idx >> 4, c8 = idx & 15;
      int gr = rb + row; if (gr >= N_NODES) gr = N_NODES - 1;
      float4 v = *(const float4*)&hin16[(size_t)gr * HD + c8 * 8];
      __half2* hv = (__half2*)&v;
      #pragma unroll
      for (int q = 0; q < 4; q++) As2[(4 * c8 + q) * 128 + row] = hv[q];
    }
  }
  __syncthreads();

  float acc[4][8];
  #pragma unroll
  for (int i = 0; i < 4; i++)
    #pragma unroll
    for (int j = 0; j < 8; j++) acc[i][j] = 0.f;

  #pragma unroll 4
  for (int k2 = 0; k2 < 64; k2++){
    float4 ar0 = *(const float4*)&As2[k2 * 128 + ty * 4];
    float4 wr0 = *(const float4*)&Wh2[k2 * 128 + tx * 4];
    float4 wr1 = *(const float4*)&Wh2[k2 * 128 + 64 + tx * 4];
    const h2_t* av = (const h2_t*)&ar0;
    const h2_t* wv0 = (const h2_t*)&wr0;
    const h2_t* wv1 = (const h2_t*)&wr1;
    #pragma unroll
    for (int i = 0; i < 4; i++){
      h2_t ai = av[i];
      #pragma unroll
      for (int j = 0; j < 4; j++){
        acc[i][j]     = fdot2f(ai, wv0[j], acc[i][j]);
        acc[i][j + 4] = fdot2f(ai, wv1[j], acc[i][j + 4]);
      }
    }
  }

  #pragma unroll
  for (int i = 0; i < 4; i++){
    int r = rb + ty * 4 + i;
    if (r < N_NODES){
      float2 s0, s1;
      ((__half2*)&s0)[0] = __floats2half2_rn(acc[i][0], acc[i][1]);
      ((__half2*)&s0)[1] = __floats2half2_rn(acc[i][2], acc[i][3]);
      ((__half2*)&s1)[0] = __floats2half2_rn(acc[i][4], acc[i][5]);
      ((__half2*)&s1)[1] = __floats2half2_rn(acc[i][6], acc[i][7]);
      *(float2*)&hp_h[(size_t)r * HD + tx * 4]      = s0;
      *(float2*)&hp_h[(size_t)r * HD + 64 + tx * 4] = s1;
    }
  }

  float as_v[8], ad_v[8];
  #pragma unroll
  for (int j = 0; j < 4; j++){
    as_v[j]     = as_[tx * 4 + j];      ad_v[j]     = ad_[tx * 4 + j];
    as_v[j + 4] = as_[64 + tx * 4 + j]; ad_v[j + 4] = ad_[64 + tx * 4 + j];
  }
  #pragma unroll
  for (int i = 0; i < 4; i++){
    float ps = 0.f, pd = 0.f;
    #pragma unroll
    for (int j = 0; j < 8; j++){
      ps = fmaf(acc[i][j], as_v[j], ps);
      pd = fmaf(acc[i][j], ad_v[j], pd);
    }
    #pragma unroll
    for (int off = 8; off > 0; off >>= 1){
      ps += __shfl_down(ps, off, 16);
      pd += __shfl_down(pd, off, 16);
    }
    int r = rb + ty * 4 + i;
    if (tx == 0 && r < N_NODES){ ssrc[r] = ps; sdst[r] = pd; }
  }
}

// layer-0 dispatch: gemm0 (f32 A direct) + CSR bucket fill
__global__ __launch_bounds__(512, 4) void fillgemm_kernel(const float* __restrict__ x,
                                                          const __half2* __restrict__ Wt,
                                                          __half* __restrict__ hp_h,
                                                          const float* __restrict__ as_,
                                                          const float* __restrict__ ad_,
                                                          float* __restrict__ ssrc,
                                                          float* __restrict__ sdst,
                                                          const int* __restrict__ src32,
                                                          const int* __restrict__ dst32,
                                                          int* rowcur, int2* __restrict__ csr){
  __shared__ __align__(16) __half2 As2[64 * 128];   // 32KB
  __shared__ __align__(16) __half2 Wh2[64 * 128];   // 32KB
  int b = blockIdx.x;
  if (b < GB){
    gemm_tile512<true>(b, threadIdx.x, As2, Wh2, x, Wt, hp_h, as_, ad_, ssrc, sdst);
  } else {
    int gtid = (b - GB) * 512 + threadIdx.x;
    for (int e = gtid; e < TOT; e += FILLB * 512){
      int s, d;
      if (e < N_EDGES){
        s = src32[e];
        d = dst32[e];
      } else {
        s = d = e - N_EDGES;
      }
      int pos = atomicAdd(&rowcur[d], 1);
      csr[pos] = make_int2(s, e);
    }
  }
}

__global__ __launch_bounds__(512, 4) void gemm_kernel(const __half* __restrict__ hin,
                                                      const __half2* __restrict__ Wt,
                                                      __half* __restrict__ hp_h,
                                                      const float* __restrict__ as_,
                                                      const float* __restrict__ ad_,
                                                      float* __restrict__ ssrc,
                                                      float* __restrict__ sdst){
  __shared__ __align__(16) __half2 As2[64 * 128];
  __shared__ __align__(16) __half2 Wh2[64 * 128];
  gemm_tile512<false>(blockIdx.x, threadIdx.x, As2, Wh2, hin, Wt, hp_h, as_, ad_, ssrc, sdst);
}

// ---------- column-sliced fused attention + aggregation ----------
// Block (g, s=b&3) covers node-group g (32 nodes) x column-slice s (32 cols).
// Per-XCD working set = hp[:, slice] = 3.2MB -> fits 4MB L2; gather becomes
// L2-resident. Edge metadata re-read x4 but streaming/L3-resident. 8 lanes
// per node (8B each), x8 edge unroll, exp recomputed per slice (cheap VALU).
// hp viewed as float2 (4 halves): row stride = 128/4 = 32; col offset = cb/4.
__global__ __launch_bounds__(256) void agg_kernel(const int* __restrict__ rowstart,
                                                  const int2* __restrict__ csr,
                                                  const float* __restrict__ eattr,
                                                  const float* __restrict__ ssrc,
                                                  const float* __restrict__ sdst,
                                                  const float* __restrict__ scal, int which,
                                                  const __half* __restrict__ hp_h,
                                                  const float* __restrict__ bias,
                                                  __half* __restrict__ hnext,
                                                  float* __restrict__ out, int outoff,
                                                  const float* __restrict__ xsrc){
  int b = blockIdx.x;
  if (b >= AGB2){
    // x -> out[:,0:128] streaming copy (layer 0 only), nontemporal
    int base = (b - AGB2) * 1024 + threadIdx.x;
    #pragma unroll
    for (int u = 0; u < 4; u++){
      int idx = base + u * 256;
      if (idx < N_NODES * HD / 4){
        int n = idx >> 5, c4 = idx & 31;
        f4_t v = __builtin_nontemporal_load((const f4_t*)xsrc + idx);
        __builtin_nontemporal_store(v, (f4_t*)&out[(size_t)n * OUTW + c4 * 4]);
      }
    }
    return;
  }
  int s   = b & 3;                  // column slice
  int g   = b >> 2;                 // node group
  int sub = threadIdx.x >> 3;       // 0..31 node slot
  int lane= threadIdx.x & 7;        // covers cols cb..cb+3
  int n = g * 32 + sub;
  if (n >= N_NODES) return;
  int s0 = rowstart[n];
  int s1 = (n + 1 < N_NODES) ? rowstart[n + 1] : TOT;
  float sd = sdst[n];
  float ce = scal[1 + which];
  float mean_ea = scal[0] * (1.0f / (float)N_EDGES);
  int cb = s * 32 + lane * 4;       // column base within the 128
  float4 b4 = *(const float4*)&bias[cb];
  const float2* hb = (const float2*)hp_h;   // 4 halves per float2; row stride 32
  size_t coff = (size_t)(cb >> 2);          // s*8 + lane

  float a0 = 0.f, a1 = 0.f, a2 = 0.f, a3 = 0.f;
  float sum = 0.f;

#define EW(se) ({ float eav = ((se).y < N_EDGES) ? eattr[(se).y] : mean_ea;       \
    float al = ssrc[(se).x] + sd + eav * ce;                                      \
    al = (al >= 0.f) ? al : NEG_SLOPE * al;                                       \
    expf(al); })

#define ACC4(r, p) { const __half2* hh = (const __half2*)&(r); float2 f;         \
    f = __half22float2(hh[0]); a0 = fmaf(p, f.x, a0); a1 = fmaf(p, f.y, a1);     \
    f = __half22float2(hh[1]); a2 = fmaf(p, f.x, a2); a3 = fmaf(p, f.y, a3); }

  int i = s0;
  for (; i + 8 <= s1; i += 8){
    int2 se[8]; float2 r[8];
    #pragma unroll
    for (int u = 0; u < 8; u++) se[u] = csr[i + u];
    #pragma unroll
    for (int u = 0; u < 8; u++) r[u] = hb[(size_t)se[u].x * 32 + coff];
    #pragma unroll
    for (int u = 0; u < 8; u++){
      float p = EW(se[u]);
      sum += p;
      ACC4(r[u], p);
    }
  }
  for (; i < s1; i++){
    int2 se = csr[i];
    float2 r = hb[(size_t)se.x * 32 + coff];
    float p = EW(se);
    sum += p;
    ACC4(r, p);
  }
#undef ACC4
#undef EW

  float inv = 1.0f / (sum + 1e-16f);
  float v0 = fmaf(a0, inv, b4.x); v0 = v0 > 0.f ? v0 : 0.f;
  float v1 = fmaf(a1, inv, b4.y); v1 = v1 > 0.f ? v1 : 0.f;
  float v2 = fmaf(a2, inv, b4.z); v2 = v2 > 0.f ? v2 : 0.f;
  float v3 = fmaf(a3, inv, b4.w); v3 = v3 > 0.f ? v3 : 0.f;
  if (hnext){
    float2 pk;
    __half2* p2h = (__half2*)&pk;
    p2h[0] = __floats2half2_rn(v0, v1);
    p2h[1] = __floats2half2_rn(v2, v3);
    *(float2*)&hnext[(size_t)n * HD + cb] = pk;
  }
  nt_store4(&out[(size_t)n * OUTW + outoff + cb], v0, v1, v2, v3);
}

// ---------- launch ----------

extern "C" void kernel_launch(void* const* d_in, const int* in_sizes, int n_in,
                              void* d_out, int out_size, void* d_ws, size_t ws_size,
                              hipStream_t stream){
  (void)in_sizes; (void)n_in; (void)out_size; (void)ws_size;
  const float* x    = (const float*)d_in[0];
  const void*  ei   = d_in[1];
  const float* eatt = (const float*)d_in[2];
  const float* W0   = (const float*)d_in[3];
  const float* as0  = (const float*)d_in[4];
  const float* ad0  = (const float*)d_in[5];
  const float* We0  = (const float*)d_in[6];
  const float* ae0  = (const float*)d_in[7];
  const float* b0   = (const float*)d_in[8];
  const float* W1   = (const float*)d_in[9];
  const float* as1  = (const float*)d_in[10];
  const float* ad1  = (const float*)d_in[11];
  const float* We1  = (const float*)d_in[12];
  const float* ae1  = (const float*)d_in[13];
  const float* b1   = (const float*)d_in[14];
  float* out = (float*)d_out;

  char* ws = (char*)d_ws;
  size_t off = 0;
  auto alloc = [&](size_t bytes) -> void* {
    void* p = ws + off;
    off += (bytes + 255) & ~(size_t)255;
    return p;
  };
  __half*   hp_h     = (__half*)  alloc((size_t)N_NODES * HD * 2);
  __half*   h1       = (__half*)  alloc((size_t)N_NODES * HD * 2);
  float*    ssrc     = (float*)   alloc((size_t)N_NODES * 4);
  float*    sdst     = (float*)   alloc((size_t)N_NODES * 4);
  // deg + scal + chunkflag contiguous: ONE memset zeroes all three
  int*      deg      = (int*)     alloc((size_t)N_NODES * 4);   // 200000 -> padded 200192
  float*    scal     = (float*)   alloc(256);                   // [0]=sum(ea) [1]=ce0 [2]=ce1
  int*      chunkflag= (int*)     alloc(256);                   // [c] = chunk_total+1 (0 = unset)
  int*      rowstart = (int*)     alloc((size_t)N_NODES * 4);
  int*      rowcur   = (int*)     alloc((size_t)N_NODES * 4);
  int*      src32    = (int*)     alloc((size_t)N_EDGES * 4);
  int*      dst32    = (int*)     alloc((size_t)N_EDGES * 4);
  int2*     csr      = (int2*)    alloc((size_t)TOT * 8);
  __half2*  Wt0      = (__half2*) alloc((size_t)8192 * 4);
  __half2*  Wt1      = (__half2*) alloc((size_t)8192 * 4);

  (void)hipMemsetAsync(deg, 0, 200192 + 256 + 256, stream);

  edge_kernel<<<DBLK + WBLK + SBLK + 1, 256, 0, stream>>>(
      ei, deg, src32, dst32, W0, W1, Wt0, Wt1, eatt, scal, We0, ae0, We1, ae1);
  scanfuse_kernel<<<NCHUNK, 256, 0, stream>>>(deg, rowstart, rowcur, chunkflag);

  // layer 0: gemm0 (f32 A) + CSR bucket fill in one dispatch
  fillgemm_kernel<<<GB + FILLB, 512, 0, stream>>>(x, Wt0, hp_h, as0, ad0, ssrc, sdst,
                                                  src32, dst32, rowcur, csr);
  // agg0 (column-sliced) + x->out copy blocks
  agg_kernel<<<AGB2 + XC, 256, 0, stream>>>(rowstart, csr, eatt, ssrc, sdst, scal, 0,
                                            hp_h, b0, h1, out, 128, x);

  // layer 1
  gemm_kernel<<<GB, 512, 0, stream>>>(h1, Wt1, hp_h, as1, ad1, ssrc, sdst);
  agg_kernel<<<AGB2, 256, 0, stream>>>(rowstart, csr, eatt, ssrc, sdst, scal, 1,
                                       hp_h, b1, nullptr, out, 256, nullptr);
}

// Round 11
// 296.096 us; speedup vs baseline: 1.2368x; 1.2368x over previous
//
#include <hip/hip_runtime.h>
#include <hip/hip_fp16.h>
#include <math.h>

#define N_NODES 50000
#define N_EDGES 600000
#define TOT (N_EDGES + N_NODES)   // 650000 edges incl. self-loops
#define HD 128
#define OUTW 384
#define NEG_SLOPE 0.2f

#define BM 128
#define GB 391          // ceil(50000/128) gemm tiles
#define AGB 3125        // 50000/16 agg node-groups (exact)
#define NCHUNK 49       // ceil(50000/1024)
#define FILLB 256       // fill blocks inside fillgemm dispatch
#define XC 1563         // xcopy blocks inside fillgemm dispatch (1563*1024 >= 1.6M float4)

// edge_kernel block ranges
#define DBLK 2540       // edge decode + degree count
#define WBLK 64         // W pack
#define SBLK 64         // edge_attr sum
// +1 block: We.ae dots

// ---------- helpers ----------

typedef _Float16 h2_t __attribute__((ext_vector_type(2)));
typedef float f4_t __attribute__((ext_vector_type(4)));   // native vec for nontemporal builtins

static __device__ __forceinline__ float fdot2f(h2_t a, h2_t b, float c){
#if __has_builtin(__builtin_amdgcn_fdot2)
  return __builtin_amdgcn_fdot2(a, b, c, false);
#else
  return fmaf((float)a[0], (float)b[0], fmaf((float)a[1], (float)b[1], c));
#endif
}

static __device__ __forceinline__ void nt_store4(float* p, float a, float b, float c, float d){
  f4_t v = {a, b, c, d};
  __builtin_nontemporal_store(v, (f4_t*)p);
}

static __device__ __forceinline__ int load_edge(const void* ei, int is64, long long off){
  return is64 ? (int)((const long long*)ei)[off] : ((const int*)ei)[off];
}

// ---------- edge/setup kernel (critical-path-only work) ----------
__global__ __launch_bounds__(256) void edge_kernel(const void* ei, int* deg,
                                                   int* __restrict__ src32, int* __restrict__ dst32,
                                                   const float* __restrict__ W0, const float* __restrict__ W1,
                                                   __half2* __restrict__ Wt0, __half2* __restrict__ Wt1,
                                                   const float* __restrict__ eattr, float* scal,
                                                   const float* __restrict__ We0, const float* __restrict__ ae0,
                                                   const float* __restrict__ We1, const float* __restrict__ ae1){
  int b = blockIdx.x;
  int t = threadIdx.x;
  if (b < DBLK){
    __shared__ int s_is64;
    if (t < 64){
      long long v = ((const long long*)ei)[t];
      unsigned long long bad = __ballot(v < 0 || v >= N_NODES);
      if (t == 0) s_is64 = (bad == 0ull) ? 1 : 0;
    }
    __syncthreads();
    int is64 = s_is64;
    int e = b * 256 + t;
    if (e < TOT){
      int d;
      if (e < N_EDGES){
        int s = load_edge(ei, is64, e);
        d = load_edge(ei, is64, (long long)N_EDGES + e);
        src32[e] = s;
        dst32[e] = d;
      } else {
        d = e - N_EDGES;
      }
      atomicAdd(&deg[d], 1);
    }
  } else if (b < DBLK + WBLK){
    int e = (b - DBLK) * 256 + t;             // 0..16383 exact
    const float* W = (e < 8192) ? W0 : W1;
    __half2* Wt = (e < 8192) ? Wt0 : Wt1;
    int i = e & 8191;
    int n = i & 127, k2 = i >> 7;
    float a = W[n * HD + 2 * k2];
    float c = W[n * HD + 2 * k2 + 1];
    Wt[k2 * 128 + n] = __floats2half2_rn(a, c);
  } else if (b < DBLK + WBLK + SBLK){
    int gtid = (b - DBLK - WBLK) * 256 + t;
    float s = 0.f;
    for (int i = gtid; i < N_EDGES; i += SBLK * 256) s += eattr[i];
    #pragma unroll
    for (int o = 32; o > 0; o >>= 1) s += __shfl_down(s, o, 64);
    if ((t & 63) == 0) atomicAdd(&scal[0], s);
  } else {
    int w = t >> 6, lane = t & 63;
    if (w == 1){
      float s = We0[lane] * ae0[lane] + We0[lane + 64] * ae0[lane + 64];
      #pragma unroll
      for (int o = 32; o > 0; o >>= 1) s += __shfl_down(s, o, 64);
      if (lane == 0) scal[1] = s;
    } else if (w == 2){
      float s = We1[lane] * ae1[lane] + We1[lane + 64] * ae1[lane + 64];
      #pragma unroll
      for (int o = 32; o > 0; o >>= 1) s += __shfl_down(s, o, 64);
      if (lane == 0) scal[2] = s;
    }
  }
}

// ---------- fused CSR scan: per-chunk scan + decoupled lookback ----------
__global__ __launch_bounds__(256) void scanfuse_kernel(const int* __restrict__ deg,
                                                       int* __restrict__ rowstart,
                                                       int* __restrict__ rowcur,
                                                       int* chunkflag){
  __shared__ int sums[256];
  __shared__ int soff;
  int bid = blockIdx.x, t = threadIdx.x;
  int base = bid * 1024 + t * 4;
  int v[4];
  #pragma unroll
  for (int i = 0; i < 4; i++) v[i] = (base + i < N_NODES) ? deg[base + i] : 0;
  int tsum = v[0] + v[1] + v[2] + v[3];
  sums[t] = tsum;
  __syncthreads();
  for (int off = 1; off < 256; off <<= 1){
    int add = (t >= off) ? sums[t - off] : 0;
    __syncthreads();
    sums[t] += add;
    __syncthreads();
  }
  int run = sums[t] - tsum;

  if (t == 255)
    __hip_atomic_store(&chunkflag[bid], sums[255] + 1, __ATOMIC_RELEASE, __HIP_MEMORY_SCOPE_AGENT);

  if (t < 64){
    int acc_ = 0;
    for (int j = t; j < bid; j += 64){
      int val;
      long long spins = 0;
      while ((val = __hip_atomic_load(&chunkflag[j], __ATOMIC_ACQUIRE, __HIP_MEMORY_SCOPE_AGENT)) == 0){
        __builtin_amdgcn_s_sleep(1);
        if (++spins > (1LL << 24)) break;
      }
      acc_ += val - 1;
    }
    #pragma unroll
    for (int o = 32; o > 0; o >>= 1) acc_ += __shfl_down(acc_, o, 64);
    if (t == 0) soff = acc_;
  }
  __syncthreads();
  int off = soff;
  #pragma unroll
  for (int i = 0; i < 4; i++){
    if (base + i < N_NODES){
      int r = run + off;
      rowstart[base + i] = r;
      rowcur[base + i] = r;
    }
    run += v[i];
  }
}

// ---------- 512-thread GEMM tile (16 waves/CU at 64KB LDS) ----------
template<bool F32>
__device__ __forceinline__ void gemm_tile512(int tb, int t, __half2* As2, __half2* Wh2,
                                             const void* __restrict__ hin,
                                             const __half2* __restrict__ Wt,
                                             __half* __restrict__ hp_h,
                                             const float* __restrict__ as_,
                                             const float* __restrict__ ad_,
                                             float* __restrict__ ssrc,
                                             float* __restrict__ sdst){
  int tx = t & 15;
  int ty = t >> 4;                 // 0..31
  int rb = tb * BM;

  {
    const float4* src = (const float4*)Wt;
    float4* dst = (float4*)Wh2;
    #pragma unroll
    for (int p = 0; p < 4; p++) dst[t + p * 512] = src[t + p * 512];
  }
  if (F32){
    const float* xin = (const float*)hin;
    #pragma unroll
    for (int p = 0; p < 8; p++){
      int idx = t + p * 512;
      int row = idx >> 5, c4 = idx & 31;
      int gr = rb + row; if (gr >= N_NODES) gr = N_NODES - 1;
      float4 v = *(const float4*)&xin[(size_t)gr * HD + c4 * 4];
      As2[(2 * c4 + 0) * 128 + row] = __floats2half2_rn(v.x, v.y);
      As2[(2 * c4 + 1) * 128 + row] = __floats2half2_rn(v.z, v.w);
    }
  } else {
    const __half* hin16 = (const __half*)hin;
    #pragma unroll
    for (int p = 0; p < 4; p++){
      int idx = t + p * 512;
      int row = idx >> 4, c8 = idx & 15;
      int gr = rb + row; if (gr >= N_NODES) gr = N_NODES - 1;
      float4 v = *(const float4*)&hin16[(size_t)gr * HD + c8 * 8];
      __half2* hv = (__half2*)&v;
      #pragma unroll
      for (int q = 0; q < 4; q++) As2[(4 * c8 + q) * 128 + row] = hv[q];
    }
  }
  __syncthreads();

  float acc[4][8];
  #pragma unroll
  for (int i = 0; i < 4; i++)
    #pragma unroll
    for (int j = 0; j < 8; j++) acc[i][j] = 0.f;

  #pragma unroll 4
  for (int k2 = 0; k2 < 64; k2++){
    float4 ar0 = *(const float4*)&As2[k2 * 128 + ty * 4];
    float4 wr0 = *(const float4*)&Wh2[k2 * 128 + tx * 4];
    float4 wr1 = *(const float4*)&Wh2[k2 * 128 + 64 + tx * 4];
    const h2_t* av = (const h2_t*)&ar0;
    const h2_t* wv0 = (const h2_t*)&wr0;
    const h2_t* wv1 = (const h2_t*)&wr1;
    #pragma unroll
    for (int i = 0; i < 4; i++){
      h2_t ai = av[i];
      #pragma unroll
      for (int j = 0; j < 4; j++){
        acc[i][j]     = fdot2f(ai, wv0[j], acc[i][j]);
        acc[i][j + 4] = fdot2f(ai, wv1[j], acc[i][j + 4]);
      }
    }
  }

  #pragma unroll
  for (int i = 0; i < 4; i++){
    int r = rb + ty * 4 + i;
    if (r < N_NODES){
      float2 s0, s1;
      ((__half2*)&s0)[0] = __floats2half2_rn(acc[i][0], acc[i][1]);
      ((__half2*)&s0)[1] = __floats2half2_rn(acc[i][2], acc[i][3]);
      ((__half2*)&s1)[0] = __floats2half2_rn(acc[i][4], acc[i][5]);
      ((__half2*)&s1)[1] = __floats2half2_rn(acc[i][6], acc[i][7]);
      *(float2*)&hp_h[(size_t)r * HD + tx * 4]      = s0;
      *(float2*)&hp_h[(size_t)r * HD + 64 + tx * 4] = s1;
    }
  }

  float as_v[8], ad_v[8];
  #pragma unroll
  for (int j = 0; j < 4; j++){
    as_v[j]     = as_[tx * 4 + j];      ad_v[j]     = ad_[tx * 4 + j];
    as_v[j + 4] = as_[64 + tx * 4 + j]; ad_v[j + 4] = ad_[64 + tx * 4 + j];
  }
  #pragma unroll
  for (int i = 0; i < 4; i++){
    float ps = 0.f, pd = 0.f;
    #pragma unroll
    for (int j = 0; j < 8; j++){
      ps = fmaf(acc[i][j], as_v[j], ps);
      pd = fmaf(acc[i][j], ad_v[j], pd);
    }
    #pragma unroll
    for (int off = 8; off > 0; off >>= 1){
      ps += __shfl_down(ps, off, 16);
      pd += __shfl_down(pd, off, 16);
    }
    int r = rb + ty * 4 + i;
    if (tx == 0 && r < N_NODES){ ssrc[r] = ps; sdst[r] = pd; }
  }
}

// layer-0 dispatch: gemm0 (f32 A direct) + CSR bucket fill (stores edge-attr
// VALUE in csr.y — removes the random eattr gather from both agg passes)
// + x->out[:,0:128] copy blocks
__global__ __launch_bounds__(512, 4) void fillgemm_kernel(const float* __restrict__ x,
                                                          const __half2* __restrict__ Wt,
                                                          __half* __restrict__ hp_h,
                                                          const float* __restrict__ as_,
                                                          const float* __restrict__ ad_,
                                                          float* __restrict__ ssrc,
                                                          float* __restrict__ sdst,
                                                          const int* __restrict__ src32,
                                                          const int* __restrict__ dst32,
                                                          const float* __restrict__ eattr,
                                                          const float* __restrict__ scal,
                                                          int* rowcur, int2* __restrict__ csr,
                                                          float* __restrict__ out){
  __shared__ __align__(16) __half2 As2[64 * 128];   // 32KB
  __shared__ __align__(16) __half2 Wh2[64 * 128];   // 32KB
  int b = blockIdx.x;
  if (b < GB){
    gemm_tile512<true>(b, threadIdx.x, As2, Wh2, x, Wt, hp_h, as_, ad_, ssrc, sdst);
  } else if (b < GB + FILLB){
    float mean_ea = scal[0] * (1.0f / (float)N_EDGES);
    int gtid = (b - GB) * 512 + threadIdx.x;
    for (int e = gtid; e < TOT; e += FILLB * 512){
      int s, d; float ea;
      if (e < N_EDGES){
        s = src32[e];
        d = dst32[e];
        ea = eattr[e];
      } else {
        s = d = e - N_EDGES;
        ea = mean_ea;
      }
      int pos = atomicAdd(&rowcur[d], 1);
      csr[pos] = make_int2(s, __float_as_int(ea));
    }
  } else {
    int base = (b - GB - FILLB) * 1024 + threadIdx.x;   // 2 float4s per thread
    #pragma unroll
    for (int u = 0; u < 2; u++){
      int idx = base + u * 512;
      if (idx < N_NODES * HD / 4){
        int n = idx >> 5, c4 = idx & 31;
        float4 v = ((const float4*)x)[idx];
        *(float4*)&out[(size_t)n * OUTW + c4 * 4] = v;
      }
    }
  }
}

__global__ __launch_bounds__(512, 4) void gemm_kernel(const __half* __restrict__ hin,
                                                      const __half2* __restrict__ Wt,
                                                      __half* __restrict__ hp_h,
                                                      const float* __restrict__ as_,
                                                      const float* __restrict__ ad_,
                                                      float* __restrict__ ssrc,
                                                      float* __restrict__ sdst){
  __shared__ __align__(16) __half2 As2[64 * 128];
  __shared__ __align__(16) __half2 Wh2[64 * 128];
  gemm_tile512<false>(blockIdx.x, threadIdx.x, As2, Wh2, hin, Wt, hp_h, as_, ad_, ssrc, sdst);
}

// ---------- fused attention + aggregation ----------
// 16 lanes per dst node (16 nodes per 256-block), inline exp-weights,
// x8 arrayed unroll. Edge-attr value is embedded in csr.y (bitcast float) —
// per-edge critical path has ONE random gather (hp row) + one L2-resident
// ssrc read. NT stores for out (never re-read).
__global__ __launch_bounds__(256) void agg_kernel(const int* __restrict__ rowstart,
                                                  const int2* __restrict__ csr,
                                                  const float* __restrict__ ssrc,
                                                  const float* __restrict__ sdst,
                                                  const float* __restrict__ scal, int which,
                                                  const __half* __restrict__ hp_h,
                                                  const float* __restrict__ bias,
                                                  __half* __restrict__ hnext,
                                                  float* __restrict__ out, int outoff){
  int sub  = threadIdx.x >> 4;
  int lane = threadIdx.x & 15;
  int n = blockIdx.x * 16 + sub;        // AGB*16 == N_NODES exactly
  int s0 = rowstart[n];
  int s1 = (n + 1 < N_NODES) ? rowstart[n + 1] : TOT;
  float sd = sdst[n];
  float ce = scal[1 + which];
  float4 bA = *(const float4*)&bias[lane * 8];
  float4 bB = *(const float4*)&bias[lane * 8 + 4];
  const float4* hb = (const float4*)hp_h;   // one float4 = 8 halves; row stride = 16

  float a0 = 0.f, a1 = 0.f, a2 = 0.f, a3 = 0.f;
  float a4 = 0.f, a5 = 0.f, a6 = 0.f, a7 = 0.f;
  float sum = 0.f;

#define EW(se) ({ float al = ssrc[(se).x] + sd + __int_as_float((se).y) * ce;     \
    al = (al >= 0.f) ? al : NEG_SLOPE * al;                                       \
    expf(al); })

#define ACC8(r, p) { const __half2* hh = (const __half2*)&(r); float2 f;         \
    f = __half22float2(hh[0]); a0 = fmaf(p, f.x, a0); a1 = fmaf(p, f.y, a1);     \
    f = __half22float2(hh[1]); a2 = fmaf(p, f.x, a2); a3 = fmaf(p, f.y, a3);     \
    f = __half22float2(hh[2]); a4 = fmaf(p, f.x, a4); a5 = fmaf(p, f.y, a5);     \
    f = __half22float2(hh[3]); a6 = fmaf(p, f.x, a6); a7 = fmaf(p, f.y, a7); }

  int i = s0;
  for (; i + 8 <= s1; i += 8){
    int2 se[8]; float4 r[8];
    #pragma unroll
    for (int u = 0; u < 8; u++) se[u] = csr[i + u];
    #pragma unroll
    for (int u = 0; u < 8; u++) r[u] = hb[(size_t)se[u].x * 16 + lane];
    #pragma unroll
    for (int u = 0; u < 8; u++){
      float p = EW(se[u]);
      sum += p;
      ACC8(r[u], p);
    }
  }
  for (; i < s1; i++){
    int2 se = csr[i];
    float4 r = hb[(size_t)se.x * 16 + lane];
    float p = EW(se);
    sum += p;
    ACC8(r, p);
  }
#undef ACC8
#undef EW

  float inv = 1.0f / (sum + 1e-16f);
  float v0 = fmaf(a0, inv, bA.x); v0 = v0 > 0.f ? v0 : 0.f;
  float v1 = fmaf(a1, inv, bA.y); v1 = v1 > 0.f ? v1 : 0.f;
  float v2 = fmaf(a2, inv, bA.z); v2 = v2 > 0.f ? v2 : 0.f;
  float v3 = fmaf(a3, inv, bA.w); v3 = v3 > 0.f ? v3 : 0.f;
  float v4 = fmaf(a4, inv, bB.x); v4 = v4 > 0.f ? v4 : 0.f;
  float v5 = fmaf(a5, inv, bB.y); v5 = v5 > 0.f ? v5 : 0.f;
  float v6 = fmaf(a6, inv, bB.z); v6 = v6 > 0.f ? v6 : 0.f;
  float v7 = fmaf(a7, inv, bB.w); v7 = v7 > 0.f ? v7 : 0.f;
  if (hnext){
    float4 pk;
    __half2* p2h = (__half2*)&pk;
    p2h[0] = __floats2half2_rn(v0, v1);
    p2h[1] = __floats2half2_rn(v2, v3);
    p2h[2] = __floats2half2_rn(v4, v5);
    p2h[3] = __floats2half2_rn(v6, v7);
    *(float4*)&hnext[(size_t)n * HD + lane * 8] = pk;
  }
  nt_store4(&out[(size_t)n * OUTW + outoff + lane * 8],     v0, v1, v2, v3);
  nt_store4(&out[(size_t)n * OUTW + outoff + lane * 8 + 4], v4, v5, v6, v7);
}

// ---------- launch ----------

extern "C" void kernel_launch(void* const* d_in, const int* in_sizes, int n_in,
                              void* d_out, int out_size, void* d_ws, size_t ws_size,
                              hipStream_t stream){
  (void)in_sizes; (void)n_in; (void)out_size; (void)ws_size;
  const float* x    = (const float*)d_in[0];
  const void*  ei   = d_in[1];
  const float* eatt = (const float*)d_in[2];
  const float* W0   = (const float*)d_in[3];
  const float* as0  = (const float*)d_in[4];
  const float* ad0  = (const float*)d_in[5];
  const float* We0  = (const float*)d_in[6];
  const float* ae0  = (const float*)d_in[7];
  const float* b0   = (const float*)d_in[8];
  const float* W1   = (const float*)d_in[9];
  const float* as1  = (const float*)d_in[10];
  const float* ad1  = (const float*)d_in[11];
  const float* We1  = (const float*)d_in[12];
  const float* ae1  = (const float*)d_in[13];
  const float* b1   = (const float*)d_in[14];
  float* out = (float*)d_out;

  char* ws = (char*)d_ws;
  size_t off = 0;
  auto alloc = [&](size_t bytes) -> void* {
    void* p = ws + off;
    off += (bytes + 255) & ~(size_t)255;
    return p;
  };
  __half*   hp_h     = (__half*)  alloc((size_t)N_NODES * HD * 2);
  __half*   h1       = (__half*)  alloc((size_t)N_NODES * HD * 2);
  float*    ssrc     = (float*)   alloc((size_t)N_NODES * 4);
  float*    sdst     = (float*)   alloc((size_t)N_NODES * 4);
  // deg + scal + chunkflag contiguous: ONE memset zeroes all three
  int*      deg      = (int*)     alloc((size_t)N_NODES * 4);   // 200000 -> padded 200192
  float*    scal     = (float*)   alloc(256);                   // [0]=sum(ea) [1]=ce0 [2]=ce1
  int*      chunkflag= (int*)     alloc(256);                   // [c] = chunk_total+1 (0 = unset)
  int*      rowstart = (int*)     alloc((size_t)N_NODES * 4);
  int*      rowcur   = (int*)     alloc((size_t)N_NODES * 4);
  int*      src32    = (int*)     alloc((size_t)N_EDGES * 4);
  int*      dst32    = (int*)     alloc((size_t)N_EDGES * 4);
  int2*     csr      = (int2*)    alloc((size_t)TOT * 8);
  __half2*  Wt0      = (__half2*) alloc((size_t)8192 * 4);
  __half2*  Wt1      = (__half2*) alloc((size_t)8192 * 4);

  (void)hipMemsetAsync(deg, 0, 200192 + 256 + 256, stream);

  edge_kernel<<<DBLK + WBLK + SBLK + 1, 256, 0, stream>>>(
      ei, deg, src32, dst32, W0, W1, Wt0, Wt1, eatt, scal, We0, ae0, We1, ae1);
  scanfuse_kernel<<<NCHUNK, 256, 0, stream>>>(deg, rowstart, rowcur, chunkflag);

  // layer 0: gemm0 (f32 A) + CSR fill (embeds edge-attr) + x->out copy
  fillgemm_kernel<<<GB + FILLB + XC, 512, 0, stream>>>(x, Wt0, hp_h, as0, ad0, ssrc, sdst,
                                                       src32, dst32, eatt, scal,
                                                       rowcur, csr, out);
  agg_kernel<<<AGB, 256, 0, stream>>>(rowstart, csr, ssrc, sdst, scal, 0,
                                      hp_h, b0, h1, out, 128);

  // layer 1
  gemm_kernel<<<GB, 512, 0, stream>>>(h1, Wt1, hp_h, as1, ad1, ssrc, sdst);
  agg_kernel<<<AGB, 256, 0, stream>>>(rowstart, csr, ssrc, sdst, scal, 1,
                                      hp_h, b1, nullptr, out, 256);
}